// Round 11
// baseline (102.835 us; speedup 1.0000x reference)
//
#include <hip/hip_runtime.h>
#include <hip/hip_bf16.h>

// TSM temporal shift + 1x1 conv (256->256) fused as bf16 MFMA GEMM.
// x: [128, 256, 28, 28] f32, w: [256, 256] f32, out: [128, 256, 28, 28] f32.
// out[n,o,p] = sum_c W[o,c] * Y_n[c,p],
//   Y_n[c,p] = x[n-1,c,p] (c<32, t>0), x[n+1,c,p] (32<=c<64, t<7), x[n,c,p] else.
//
// R11 = R10 + item-paired blocks: block j handles items wg and wg+896
// (n2 = n1+64, same pt/tf -> identical per-thread constants). Item2's
// half1 loads issue under item1's pass2+stores (guarded by vmcnt(56),
// FIFO: the 14 loads are oldest, stores may stay in flight); half2 issues
// under pass1 (R10 mechanism). wf loaded once per block. Peak live regs
// ~201 < 256 (2 blocks/CU budget).

#define CDIM 256
#define HWPX 784
#define FRST (CDIM * HWPX)        // 200704 floats per frame
#define P_TILE 112
#define NPT  7                    // 112-px tiles per frame
#define NWGB 896                  // blocks; item pair = (wg, wg+896), % 8 == 0
#define LROW 264                  // bf16 per LDS pixel row (528 B)

using bf16x8 = __attribute__((ext_vector_type(8))) short;
using bf16x4 = __attribute__((ext_vector_type(4))) short;
using f32x4  = __attribute__((ext_vector_type(4))) float;

static __device__ __forceinline__ unsigned int pk2(float lo, float hi) {
    union { __hip_bfloat162 h; unsigned int u; } cv;
    cv.h = __float22bfloat162_rn(make_float2(lo, hi));
    return cv.u;
}

// ---- W f32 -> bf16 row-major (one-shot) ------------------------------------
__global__ void wconv(const float* __restrict__ w, unsigned short* __restrict__ wb) {
    const int i = (blockIdx.x * 256 + threadIdx.x) * 4;
    f32x4 v = *(const f32x4*)(w + i);
    *(uint2*)(wb + i) = make_uint2(pk2(v[0], v[1]), pk2(v[2], v[3]));
}

__global__ __launch_bounds__(256, 2)   // 256-reg budget, 2 blocks/CU
void tsm_pair(const float* __restrict__ x,
              const unsigned short* __restrict__ wb,
              float* __restrict__ out) {
    __shared__ __align__(16) unsigned short y[P_TILE * LROW];   // 59136 B

    const int bid  = blockIdx.x;
    const int wg   = (bid & 7) * (NWGB / 8) + (bid >> 3);   // XCD-bijective
    const int h    = wg & 1;              // o-half (same for both items)
    const int pair = wg >> 1;             // 0..447
    const int n1   = pair / NPT;          // 0..63
    const int pt   = pair - n1 * NPT;
    const int p0   = pt * P_TILE;
    const int n2   = n1 + 64;             // item2 frame; tf identical (64%8==0)
    const int tid  = threadIdx.x;
    const int tf   = n1 & 7;

    const int lane = tid & 63;
    const int wv   = tid >> 6;
    const int g    = lane >> 4;
    const int ol   = lane & 15;

    // ---- W panel (asm-pinned once per block) ------------------------------
    bf16x8 wf[8][2];
    #pragma unroll
    for (int kk = 0; kk < 8; ++kk)
        #pragma unroll
        for (int m = 0; m < 2; ++m) {
            const unsigned short* wp =
                &wb[(size_t)(h * 128 + wv * 32 + m * 16 + ol) * CDIM + kk * 32 + g * 8];
            asm volatile("global_load_dwordx4 %0, %1, off"
                         : "=v"(wf[kk][m]) : "v"(wp));
        }

    f32x4 r0[14], r1[14];
    f32x4 acc[2][7];

    #define ISSUE(i, N_)                                                       \
    {                                                                          \
        const int idx = tid + (i) * 256;                                       \
        const int cp  = idx / 28;                                              \
        const int pv  = idx - cp * 28;                                         \
        const int c0  = cp * 2;                                                \
        const int d   = (cp < 16) ? -1 : (cp < 32 ? 1 : 0);                    \
        const bool valid = !((d == -1 && tf == 0) || (d == 1 && tf == 7));     \
        const float* s = x + ((size_t)((N_) + (valid ? d : 0)) * CDIM + c0) * HWPX \
                           + p0 + pv * 4;                                      \
        asm volatile("global_load_dwordx4 %0, %1, off" : "=v"(r0[i]) : "v"(s));\
        const float* s1 = s + HWPX;                                            \
        asm volatile("global_load_dwordx4 %0, %1, off" : "=v"(r1[i]) : "v"(s1));\
    }

    #define WRITE_ITEM(i)                                                      \
    {                                                                          \
        const int idx = tid + (i) * 256;                                       \
        const int cp  = idx / 28;                                              \
        const int pv  = idx - cp * 28;                                         \
        const int c0  = cp * 2;                                                \
        const int d   = (cp < 16) ? -1 : (cp < 32 ? 1 : 0);                    \
        const bool valid = !((d == -1 && tf == 0) || (d == 1 && tf == 7));     \
        const int cc  = c0 ^ (((pv >> 1) & 7) << 2);  /* h(p), p=pv*4+r */     \
        const int rb  = pv * 4 * LROW + cc;                                    \
        _Pragma("unroll")                                                      \
        for (int r = 0; r < 4; ++r)                                            \
            *(unsigned int*)&y[rb + r * LROW] =                                \
                valid ? pk2(r0[i][r], r1[i][r]) : 0u;                          \
    }

    #define ZERO_ACC                                                           \
    {                                                                          \
        _Pragma("unroll")                                                      \
        for (int m = 0; m < 2; ++m)                                            \
            _Pragma("unroll")                                                  \
            for (int nn = 0; nn < 7; ++nn)                                     \
                acc[m][nn] = f32x4{0.f, 0.f, 0.f, 0.f};                        \
    }

    #define COMPUTE(K0, K1)                                                    \
    {                                                                          \
        _Pragma("unroll")                                                      \
        for (int nn = 0; nn < 7; ++nn) {                                       \
            const int p    = nn * 16 + ol;                                     \
            const int zz   = ((p >> 3) & 7) << 2;                              \
            const int rowb = p * LROW;                                         \
            _Pragma("unroll")                                                  \
            for (int kk = (K0); kk < (K1); ++kk) {                             \
                const int c  = kk * 32 + g * 8;                                \
                const int e0 = c ^ zz;                                         \
                const bf16x4 lo = *(const bf16x4*)&y[rowb + e0];               \
                const bf16x4 hi = *(const bf16x4*)&y[rowb + (e0 ^ 4)];         \
                const bf16x8 bf = __builtin_shufflevector(lo, hi,              \
                                                          0, 1, 2, 3, 4, 5, 6, 7); \
                acc[0][nn] = __builtin_amdgcn_mfma_f32_16x16x32_bf16(          \
                    wf[kk][0], bf, acc[0][nn], 0, 0, 0);                       \
                acc[1][nn] = __builtin_amdgcn_mfma_f32_16x16x32_bf16(          \
                    wf[kk][1], bf, acc[1][nn], 0, 0, 0);                       \
            }                                                                  \
        }                                                                      \
    }

    #define STORES(N_)                                                         \
    {                                                                          \
        const size_t outbase = (size_t)(N_) * CDIM * HWPX + p0 + ol;           \
        _Pragma("unroll")                                                      \
        for (int m = 0; m < 2; ++m) {                                          \
            _Pragma("unroll")                                                  \
            for (int r = 0; r < 4; ++r) {                                      \
                const int o = h * 128 + wv * 32 + m * 16 + g * 4 + r;          \
                float* orow = out + outbase + (size_t)o * HWPX;                \
                _Pragma("unroll")                                              \
                for (int nn = 0; nn < 7; ++nn)                                 \
                    orow[nn * 16] = acc[m][nn][r];                             \
            }                                                                  \
        }                                                                      \
    }

    // ================== item 1 (frame n1): R10 flow =======================
    #pragma unroll
    for (int i = 0; i < 14; ++i) ISSUE(i, n1)

    // wf(16) + 28 staged outstanding; wait <=14 -> drains wf + half1
    asm volatile("s_waitcnt vmcnt(14)" ::: "memory");
    __builtin_amdgcn_sched_barrier(0);
    #pragma unroll
    for (int i = 0; i < 7; ++i) WRITE_ITEM(i)
    __syncthreads();

    ZERO_ACC
    COMPUTE(0, 4)                         // half2(item1) still flying

    asm volatile("s_waitcnt vmcnt(0)" ::: "memory");
    __builtin_amdgcn_sched_barrier(0);
    #pragma unroll
    for (int i = 7; i < 14; ++i) WRITE_ITEM(i)
    __syncthreads();

    // pass2(item1) with half1(item2) prefetch underneath
    #pragma unroll
    for (int i = 0; i < 7; ++i) ISSUE(i, n2)
    COMPUTE(4, 8)
    STORES(n1)

    // ================== item 2 (frame n2 = n1+64) =========================
    __syncthreads();                       // all waves done reading y (item1)
    // queue: 14 loads (oldest) + 56 stores; <=56 outstanding <=> loads done
    asm volatile("s_waitcnt vmcnt(56)" ::: "memory");
    __builtin_amdgcn_sched_barrier(0);
    #pragma unroll
    for (int i = 0; i < 7; ++i) WRITE_ITEM(i)
    __syncthreads();

    ZERO_ACC
    #pragma unroll
    for (int i = 7; i < 14; ++i) ISSUE(i, n2)   // half2(item2) under pass1
    COMPUTE(0, 4)

    asm volatile("s_waitcnt vmcnt(0)" ::: "memory");
    __builtin_amdgcn_sched_barrier(0);
    #pragma unroll
    for (int i = 7; i < 14; ++i) WRITE_ITEM(i)
    __syncthreads();

    COMPUTE(4, 8)
    STORES(n2)

    #undef ISSUE
    #undef WRITE_ITEM
    #undef ZERO_ACC
    #undef COMPUTE
    #undef STORES
}

// ---- fallback (no workspace): R3 kernel, known-correct ---------------------
#define LDS_STRIDE 264
__global__ __launch_bounds__(512, 4)
void tsm_fallback(const float* __restrict__ x, const float* __restrict__ w,
                  float* __restrict__ out) {
    __shared__ __align__(16) unsigned short ylds[P_TILE * LDS_STRIDE];
    const int n = blockIdx.x, tile = blockIdx.y, p0 = tile * P_TILE;
    const int tid = threadIdx.x, tf = n & 7;
    f32x4 v0[7], v1[7]; int cps[7], pvs[7];
    #pragma unroll
    for (int i = 0; i < 7; ++i) {
        const int idx = tid + i * 512, cp = idx / 28, pv = idx - cp * 28;
        cps[i] = cp; pvs[i] = pv;
        const int c0 = cp * 2;
        int nsrc; bool valid;
        if (c0 < 32)      { nsrc = n - 1; valid = (tf > 0); }
        else if (c0 < 64) { nsrc = n + 1; valid = (tf < 7); }
        else              { nsrc = n;     valid = true; }
        const float* src = x + ((size_t)(valid ? nsrc : n) * CDIM + c0) * HWPX + p0 + pv * 4;
        f32x4 a = {0,0,0,0}, b = {0,0,0,0};
        if (valid) { a = *(const f32x4*)src; b = *(const f32x4*)(src + HWPX); }
        v0[i] = a; v1[i] = b;
    }
    #pragma unroll
    for (int i = 0; i < 7; ++i) {
        const int c0 = cps[i] * 2, pv = pvs[i];
        const int cc = c0 ^ ((pv & 7) << 3);
        const int rb = pv * 4 * LDS_STRIDE + cc;
        #pragma unroll
        for (int r = 0; r < 4; ++r)
            *(unsigned int*)&ylds[rb + r * LDS_STRIDE] = pk2(v0[i][r], v1[i][r]);
    }
    __syncthreads();
    const int lane = tid & 63, wv = tid >> 6, g = lane >> 4, ol = lane & 15;
    f32x4 acc[2][7];
    #pragma unroll
    for (int m = 0; m < 2; ++m)
        #pragma unroll
        for (int nn = 0; nn < 7; ++nn) acc[m][nn] = f32x4{0,0,0,0};
    #pragma unroll
    for (int kk = 0; kk < 8; ++kk) {
        const int c = kk * 32 + g * 8;
        bf16x8 af[2];
        #pragma unroll
        for (int m = 0; m < 2; ++m) {
            const float* wp = w + (size_t)(wv * 32 + m * 16 + ol) * CDIM + c;
            f32x4 w0 = *(const f32x4*)wp, w1 = *(const f32x4*)(wp + 4);
            union { bf16x8 v; unsigned int u4[4]; } cv;
            cv.u4[0] = pk2(w0[0], w0[1]); cv.u4[1] = pk2(w0[2], w0[3]);
            cv.u4[2] = pk2(w1[0], w1[1]); cv.u4[3] = pk2(w1[2], w1[3]);
            af[m] = cv.v;
        }
        #pragma unroll
        for (int nn = 0; nn < 7; ++nn) {
            const int p = nn * 16 + ol;
            const int cc = c ^ (((p >> 2) & 7) << 3);
            const bf16x8 bf = *(const bf16x8*)&ylds[p * LDS_STRIDE + cc];
            #pragma unroll
            for (int m = 0; m < 2; ++m)
                acc[m][nn] = __builtin_amdgcn_mfma_f32_16x16x32_bf16(af[m], bf, acc[m][nn], 0, 0, 0);
        }
    }
    const size_t outbase = (size_t)n * CDIM * HWPX + p0 + ol;
    #pragma unroll
    for (int m = 0; m < 2; ++m)
        #pragma unroll
        for (int r = 0; r < 4; ++r) {
            const int o = wv * 32 + m * 16 + g * 4 + r;
            float* orow = out + outbase + (size_t)o * HWPX;
            #pragma unroll
            for (int nn = 0; nn < 7; ++nn) orow[nn * 16] = acc[m][nn][r];
        }
}

extern "C" void kernel_launch(void* const* d_in, const int* in_sizes, int n_in,
                              void* d_out, int out_size, void* d_ws, size_t ws_size,
                              hipStream_t stream) {
    const float* x = (const float*)d_in[0];
    const float* w = (const float*)d_in[1];
    float* out     = (float*)d_out;
    const size_t wb_bytes = (size_t)CDIM * CDIM * sizeof(unsigned short); // 128KB
    if (ws_size >= wb_bytes) {
        unsigned short* wbuf = (unsigned short*)d_ws;
        wconv<<<64, 256, 0, stream>>>(w, wbuf);
        tsm_pair<<<NWGB, 256, 0, stream>>>(x, wbuf, out);
    } else {
        tsm_fallback<<<dim3(128, 7, 1), dim3(512, 1, 1), 0, stream>>>(x, w, out);
    }
}

// Round 12
// 61.646 us; speedup vs baseline: 1.6681x; 1.6681x over previous
//
#include <hip/hip_runtime.h>
#include <hip/hip_bf16.h>

// TSM temporal shift + 1x1 conv (256->256) fused as bf16 MFMA GEMM.
// x: [128, 256, 28, 28] f32, w: [256, 256] f32, out: [128, 256, 28, 28] f32.
// out[n,o,p] = sum_c W[o,c] * Y_n[c,p],
//   Y_n[c,p] = x[n-1,c,p] (c<32, t>0), x[n+1,c,p] (32<=c<64, t<7), x[n,c,p] else.
//
// R12: single-x-read full-channel blocks.
//  R10/R9 audit: bytes-to-CUs = 305MB (x read TWICE via o-half twin blocks;
//  114KB tile x 64 resident blocks/XCD thrashes the 4MB L2) / 48.6us = 6.3TB/s
//  = the fabric ceiling. -> Read x once: block = 64-px tile x ALL 256 out-ch.
//  203MB total -> ~32us floor.
//  - Flattened q-space tiles (64 px, vec4-aligned, may straddle frames; each
//    item computes its own frame/shift/valid).
//  - Wave owns 64 out-ch x 64 px: acc[4][4] = 64 regs. W per K-half only:
//    wf[4][4] = 64 regs, asm-issued per pass (L2 hit, latency hidden).
//  - R10's verified K-split: vmcnt(8) -> write h1 -> pass1 (h2 flying) ->
//    issue wfB -> vmcnt(16) -> write h2 -> sync -> vmcnt(0) -> pass2.
//  - R10's verified 4-bf16 swizzle: write cc=c0^(((pv>>1)&7)<<2), read
//    e0 = c ^ (((lp>>3)&7)<<2), pairs (e0, e0^4).
//  - Plain stores at block end (R11 lesson: no in-flight store games).

#define CDIM 256
#define HWPX 784
#define FRST (CDIM * HWPX)        // 200704 floats per frame
#define TPX  64                   // pixels per tile (flattened q space)
#define NTILES 1568               // 128*784/64, % 8 == 0
#define LROW 264                  // bf16 per LDS pixel row (528 B)

using bf16x8 = __attribute__((ext_vector_type(8))) short;
using bf16x4 = __attribute__((ext_vector_type(4))) short;
using f32x4  = __attribute__((ext_vector_type(4))) float;

static __device__ __forceinline__ unsigned int pk2(float lo, float hi) {
    union { __hip_bfloat162 h; unsigned int u; } cv;
    cv.h = __float22bfloat162_rn(make_float2(lo, hi));
    return cv.u;
}

// ---- W f32 -> bf16 row-major (one-shot) ------------------------------------
__global__ void wconv(const float* __restrict__ w, unsigned short* __restrict__ wb) {
    const int i = (blockIdx.x * 256 + threadIdx.x) * 4;
    f32x4 v = *(const f32x4*)(w + i);
    *(uint2*)(wb + i) = make_uint2(pk2(v[0], v[1]), pk2(v[2], v[3]));
}

__global__ __launch_bounds__(256, 2)   // 256-reg budget, 2 blocks/CU
void tsm_full(const float* __restrict__ x,
              const unsigned short* __restrict__ wb,
              float* __restrict__ out) {
    __shared__ __align__(16) unsigned short y[TPX * LROW];   // 33792 B

    const int bid = blockIdx.x;
    const int t   = (bid & 7) * (NTILES / 8) + (bid >> 3);   // XCD-bijective
    const int tid = threadIdx.x;
    const int lane = tid & 63;
    const int wv   = tid >> 6;            // wave -> 64 out-channels
    const int g    = lane >> 4;
    const int ol   = lane & 15;

    bf16x8 wf[4][4];                      // [kk-in-half][m]
    f32x4  r0[8], r1[8];                  // staged rows c0, c0+1 per item
    f32x4  acc[4][4];                     // [m][nn]

    #define WISSUE(PASS)                                                       \
    {                                                                          \
        _Pragma("unroll")                                                      \
        for (int kkh = 0; kkh < 4; ++kkh)                                      \
            _Pragma("unroll")                                                  \
            for (int m = 0; m < 4; ++m) {                                      \
                const unsigned short* wp_ = wb +                               \
                    (size_t)(wv * 64 + m * 16 + ol) * CDIM +                   \
                    ((PASS) * 4 + kkh) * 32 + g * 8;                           \
                asm volatile("global_load_dwordx4 %0, %1, off"                 \
                             : "=v"(wf[kkh][m]) : "v"(wp_));                   \
            }                                                                  \
    }

    // item i: idx = tid + i*256; cp = idx>>4 (channel pair), pv = idx&15
    // (vec4 pixel slot). i<4 <=> cp<64 <=> channels < 128 (K half 1).
    #define ISSUE(i)                                                           \
    {                                                                          \
        const int idx = tid + (i) * 256;                                       \
        const int cp  = idx >> 4;                                              \
        const int pv  = idx & 15;                                              \
        const int c0  = cp * 2;                                                \
        const int d   = (cp < 16) ? -1 : (cp < 32 ? 1 : 0);                    \
        const int gq  = t * TPX + pv * 4;                                      \
        const int nf  = gq / HWPX;                                             \
        const int pin = gq - nf * HWPX;                                        \
        const int tf  = nf & 7;                                                \
        const bool valid = !((d == -1 && tf == 0) || (d == 1 && tf == 7));     \
        const float* s = x + ((size_t)(nf + (valid ? d : 0)) * CDIM + c0) * HWPX + pin; \
        asm volatile("global_load_dwordx4 %0, %1, off" : "=v"(r0[i]) : "v"(s));\
        const float* s1 = s + HWPX;                                            \
        asm volatile("global_load_dwordx4 %0, %1, off" : "=v"(r1[i]) : "v"(s1));\
    }

    #define WRITE_ITEM(i)                                                      \
    {                                                                          \
        const int idx = tid + (i) * 256;                                       \
        const int cp  = idx >> 4;                                              \
        const int pv  = idx & 15;                                              \
        const int c0  = cp * 2;                                                \
        const int d   = (cp < 16) ? -1 : (cp < 32 ? 1 : 0);                    \
        const int gq  = t * TPX + pv * 4;                                      \
        const int nf  = gq / HWPX;                                             \
        const int tf  = nf & 7;                                                \
        const bool valid = !((d == -1 && tf == 0) || (d == 1 && tf == 7));     \
        const int cc  = c0 ^ (((pv >> 1) & 7) << 2);   /* lp>>3 == pv>>1 */    \
        const int rb  = pv * 4 * LROW + cc;                                    \
        _Pragma("unroll")                                                      \
        for (int r = 0; r < 4; ++r)                                            \
            *(unsigned int*)&y[rb + r * LROW] =                                \
                valid ? pk2(r0[i][r], r1[i][r]) : 0u;                          \
    }

    #define COMPUTE(PASS)                                                      \
    {                                                                          \
        _Pragma("unroll")                                                      \
        for (int nn = 0; nn < 4; ++nn) {                                       \
            const int lp   = nn * 16 + ol;                                     \
            const int zz   = ((lp >> 3) & 7) << 2;                             \
            const int rowb = lp * LROW;                                        \
            _Pragma("unroll")                                                  \
            for (int kkh = 0; kkh < 4; ++kkh) {                                \
                const int c  = ((PASS) * 4 + kkh) * 32 + g * 8;                \
                const int e0 = c ^ zz;                                         \
                const bf16x4 lo = *(const bf16x4*)&y[rowb + e0];               \
                const bf16x4 hi = *(const bf16x4*)&y[rowb + (e0 ^ 4)];         \
                const bf16x8 bf = __builtin_shufflevector(lo, hi,              \
                                                          0, 1, 2, 3, 4, 5, 6, 7); \
                _Pragma("unroll")                                              \
                for (int m = 0; m < 4; ++m)                                    \
                    acc[m][nn] = __builtin_amdgcn_mfma_f32_16x16x32_bf16(      \
                        wf[kkh][m], bf, acc[m][nn], 0, 0, 0);                  \
            }                                                                  \
        }                                                                      \
    }

    // ---- prologue: W(half1) + all staging issued ---------------------------
    WISSUE(0)
    #pragma unroll
    for (int i = 0; i < 8; ++i) ISSUE(i)

    // outstanding: wfA(16) + h1(8) + h2(8); drain wfA+h1, keep h2 flying
    asm volatile("s_waitcnt vmcnt(8)" ::: "memory");
    __builtin_amdgcn_sched_barrier(0);
    #pragma unroll
    for (int i = 0; i < 4; ++i) WRITE_ITEM(i)
    __syncthreads();

    #pragma unroll
    for (int m = 0; m < 4; ++m)
        #pragma unroll
        for (int nn = 0; nn < 4; ++nn)
            acc[m][nn] = f32x4{0.f, 0.f, 0.f, 0.f};

    // ---- pass 1 (channels < 128) while half-2 loads fly --------------------
    COMPUTE(0)

    // ---- W(half2) issue; drain h2 (keep wfB flying); write half 2 ----------
    WISSUE(1)
    asm volatile("s_waitcnt vmcnt(16)" ::: "memory");   // drains h2 (oldest 8)
    __builtin_amdgcn_sched_barrier(0);
    #pragma unroll
    for (int i = 4; i < 8; ++i) WRITE_ITEM(i)
    __syncthreads();

    asm volatile("s_waitcnt vmcnt(0)" ::: "memory");    // wfB ready
    __builtin_amdgcn_sched_barrier(0);

    // ---- pass 2 (channels >= 128), same accumulators -----------------------
    COMPUTE(1)

    // ---- epilogue: plain stores (C/D col=pixel on lane&15, row=g*4+r) ------
    #pragma unroll
    for (int nn = 0; nn < 4; ++nn) {
        const int gq  = t * TPX + nn * 16 + ol;
        const int nf  = gq / HWPX;
        const int pin = gq - nf * HWPX;
        float* ob = out + (size_t)nf * FRST + pin;
        #pragma unroll
        for (int m = 0; m < 4; ++m)
            #pragma unroll
            for (int r = 0; r < 4; ++r)
                ob[(size_t)(wv * 64 + m * 16 + g * 4 + r) * HWPX] = acc[m][nn][r];
    }

    #undef WISSUE
    #undef ISSUE
    #undef WRITE_ITEM
    #undef COMPUTE
}

// ---- fallback (no workspace): R3 kernel, known-correct ---------------------
#define P_TILE 112
#define LDS_STRIDE 264
__global__ __launch_bounds__(512, 4)
void tsm_fallback(const float* __restrict__ x, const float* __restrict__ w,
                  float* __restrict__ out) {
    __shared__ __align__(16) unsigned short ylds[P_TILE * LDS_STRIDE];
    const int n = blockIdx.x, tile = blockIdx.y, p0 = tile * P_TILE;
    const int tid = threadIdx.x, tf = n & 7;
    f32x4 v0[7], v1[7]; int cps[7], pvs[7];
    #pragma unroll
    for (int i = 0; i < 7; ++i) {
        const int idx = tid + i * 512, cp = idx / 28, pv = idx - cp * 28;
        cps[i] = cp; pvs[i] = pv;
        const int c0 = cp * 2;
        int nsrc; bool valid;
        if (c0 < 32)      { nsrc = n - 1; valid = (tf > 0); }
        else if (c0 < 64) { nsrc = n + 1; valid = (tf < 7); }
        else              { nsrc = n;     valid = true; }
        const float* src = x + ((size_t)(valid ? nsrc : n) * CDIM + c0) * HWPX + p0 + pv * 4;
        f32x4 a = {0,0,0,0}, b = {0,0,0,0};
        if (valid) { a = *(const f32x4*)src; b = *(const f32x4*)(src + HWPX); }
        v0[i] = a; v1[i] = b;
    }
    #pragma unroll
    for (int i = 0; i < 7; ++i) {
        const int c0 = cps[i] * 2, pv = pvs[i];
        const int cc = c0 ^ ((pv & 7) << 3);
        const int rb = pv * 4 * LDS_STRIDE + cc;
        #pragma unroll
        for (int r = 0; r < 4; ++r)
            *(unsigned int*)&ylds[rb + r * LDS_STRIDE] = pk2(v0[i][r], v1[i][r]);
    }
    __syncthreads();
    const int lane = tid & 63, wv = tid >> 6, g = lane >> 4, ol = lane & 15;
    f32x4 acc[2][7];
    #pragma unroll
    for (int m = 0; m < 2; ++m)
        #pragma unroll
        for (int nn = 0; nn < 7; ++nn) acc[m][nn] = f32x4{0,0,0,0};
    #pragma unroll
    for (int kk = 0; kk < 8; ++kk) {
        const int c = kk * 32 + g * 8;
        bf16x8 af[2];
        #pragma unroll
        for (int m = 0; m < 2; ++m) {
            const float* wp = w + (size_t)(wv * 32 + m * 16 + ol) * CDIM + c;
            f32x4 w0 = *(const f32x4*)wp, w1 = *(const f32x4*)(wp + 4);
            union { bf16x8 v; unsigned int u4[4]; } cv;
            cv.u4[0] = pk2(w0[0], w0[1]); cv.u4[1] = pk2(w0[2], w0[3]);
            cv.u4[2] = pk2(w1[0], w1[1]); cv.u4[3] = pk2(w1[2], w1[3]);
            af[m] = cv.v;
        }
        #pragma unroll
        for (int nn = 0; nn < 7; ++nn) {
            const int p = nn * 16 + ol;
            const int cc = c ^ (((p >> 2) & 7) << 3);
            const bf16x8 bf = *(const bf16x8*)&ylds[p * LDS_STRIDE + cc];
            #pragma unroll
            for (int m = 0; m < 2; ++m)
                acc[m][nn] = __builtin_amdgcn_mfma_f32_16x16x32_bf16(af[m], bf, acc[m][nn], 0, 0, 0);
        }
    }
    const size_t outbase = (size_t)n * CDIM * HWPX + p0 + ol;
    #pragma unroll
    for (int m = 0; m < 2; ++m)
        #pragma unroll
        for (int r = 0; r < 4; ++r) {
            const int o = wv * 32 + m * 16 + g * 4 + r;
            float* orow = out + outbase + (size_t)o * HWPX;
            #pragma unroll
            for (int nn = 0; nn < 7; ++nn) orow[nn * 16] = acc[m][nn][r];
        }
}

extern "C" void kernel_launch(void* const* d_in, const int* in_sizes, int n_in,
                              void* d_out, int out_size, void* d_ws, size_t ws_size,
                              hipStream_t stream) {
    const float* x = (const float*)d_in[0];
    const float* w = (const float*)d_in[1];
    float* out     = (float*)d_out;
    const size_t wb_bytes = (size_t)CDIM * CDIM * sizeof(unsigned short); // 128KB
    if (ws_size >= wb_bytes) {
        unsigned short* wbuf = (unsigned short*)d_ws;
        wconv<<<64, 256, 0, stream>>>(w, wbuf);
        tsm_full<<<NTILES, 256, 0, stream>>>(x, wbuf, out);
    } else {
        tsm_fallback<<<dim3(128, 7, 1), dim3(512, 1, 1), 0, stream>>>(x, w, out);
    }
}

// Round 13
// 57.952 us; speedup vs baseline: 1.7745x; 1.0637x over previous
//
#include <hip/hip_runtime.h>
#include <hip/hip_bf16.h>

// TSM temporal shift + 1x1 conv (256->256) fused as bf16 MFMA GEMM.
// x: [128, 256, 28, 28] f32, w: [256, 256] f32, out: [128, 256, 28, 28] f32.
// out[n,o,p] = sum_c W[o,c] * Y_n[c,p],
//   Y_n[c,p] = x[n-1,c,p] (c<32, t>0), x[n+1,c,p] (32<=c<64, t<7), x[n,c,p] else.
//
// R13 = R10 skeleton + in-block o-half de-dup + swapped-operand stores.
//  R10 audit: 306MB CU-side (x read twice via twin o-half blocks) / 48.6us
//  = 6.3TB/s = the achievable ceiling. De-dup: ONE block stages the 112px
//  tile once and computes BOTH o-halves sequentially (wf re-issued into the
//  same regs; LDS read-only for half 2 -> no extra syncs). 203MB -> ~32us.
//  Swapped MFMA operands: D[p,o] -> thread holds 4 consecutive PIXELS ->
//  14 global_store_dwordx4 per half (was 56 dwords).
//  All other mechanisms verified in R9/R10: asm-pinned loads, counted vmcnt
//  (queue: h1 14, wfA 16, h2 14 -> vmcnt(30)/vmcnt(14)/vmcnt(0)), 4-bf16
//  swizzle pair, sched_barrier after every waitcnt.

#define CDIM 256
#define HWPX 784
#define FRST (CDIM * HWPX)        // 200704 floats per frame
#define P_TILE 112
#define NPT  7                    // 112-px tiles per frame
#define NWG  (128 * NPT)          // 896 blocks, % 8 == 0
#define LROW 264                  // bf16 per LDS pixel row (528 B)

using bf16x8 = __attribute__((ext_vector_type(8))) short;
using bf16x4 = __attribute__((ext_vector_type(4))) short;
using f32x4  = __attribute__((ext_vector_type(4))) float;

static __device__ __forceinline__ unsigned int pk2(float lo, float hi) {
    union { __hip_bfloat162 h; unsigned int u; } cv;
    cv.h = __float22bfloat162_rn(make_float2(lo, hi));
    return cv.u;
}

// ---- W f32 -> bf16 row-major (one-shot) ------------------------------------
__global__ void wconv(const float* __restrict__ w, unsigned short* __restrict__ wb) {
    const int i = (blockIdx.x * 256 + threadIdx.x) * 4;
    f32x4 v = *(const f32x4*)(w + i);
    *(uint2*)(wb + i) = make_uint2(pk2(v[0], v[1]), pk2(v[2], v[3]));
}

__global__ __launch_bounds__(256, 2)   // 256-reg budget, 2 blocks/CU (LDS-capped)
void tsm_dedup(const float* __restrict__ x,
               const unsigned short* __restrict__ wb,
               float* __restrict__ out) {
    __shared__ __align__(16) unsigned short y[P_TILE * LROW];   // 59136 B

    const int bid = blockIdx.x;
    const int wg  = (bid & 7) * (NWG / 8) + (bid >> 3);   // XCD-bijective
    const int n   = wg / NPT;             // frame
    const int pt  = wg - n * NPT;
    const int p0  = pt * P_TILE;
    const int tid = threadIdx.x;
    const int tf  = n & 7;

    const int lane = tid & 63;
    const int wv   = tid >> 6;            // wave -> 32 out-ch per half
    const int g    = lane >> 4;
    const int ol   = lane & 15;

    bf16x8 wf[8][2];                      // W frags for current half
    f32x4  r0[14], r1[14];
    f32x4  acc[2][7];

    #define WISSUE(H)                                                          \
    {                                                                          \
        _Pragma("unroll")                                                      \
        for (int kk = 0; kk < 8; ++kk)                                         \
            _Pragma("unroll")                                                  \
            for (int m = 0; m < 2; ++m) {                                      \
                const unsigned short* wp_ =                                    \
                    &wb[(size_t)((H) * 128 + wv * 32 + m * 16 + ol) * CDIM     \
                        + kk * 32 + g * 8];                                    \
                asm volatile("global_load_dwordx4 %0, %1, off"                 \
                             : "=v"(wf[kk][m]) : "v"(wp_));                    \
            }                                                                  \
    }

    #define ISSUE(i)                                                           \
    {                                                                          \
        const int idx = tid + (i) * 256;                                       \
        const int cp  = idx / 28;                                              \
        const int pv  = idx - cp * 28;                                         \
        const int c0  = cp * 2;                                                \
        const int d   = (cp < 16) ? -1 : (cp < 32 ? 1 : 0);                    \
        const bool valid = !((d == -1 && tf == 0) || (d == 1 && tf == 7));     \
        const float* s = x + ((size_t)(n + (valid ? d : 0)) * CDIM + c0) * HWPX\
                           + p0 + pv * 4;                                      \
        asm volatile("global_load_dwordx4 %0, %1, off" : "=v"(r0[i]) : "v"(s));\
        const float* s1 = s + HWPX;                                            \
        asm volatile("global_load_dwordx4 %0, %1, off" : "=v"(r1[i]) : "v"(s1));\
    }

    #define WRITE_ITEM(i)                                                      \
    {                                                                          \
        const int idx = tid + (i) * 256;                                       \
        const int cp  = idx / 28;                                              \
        const int pv  = idx - cp * 28;                                         \
        const int c0  = cp * 2;                                                \
        const int d   = (cp < 16) ? -1 : (cp < 32 ? 1 : 0);                    \
        const bool valid = !((d == -1 && tf == 0) || (d == 1 && tf == 7));     \
        const int cc  = c0 ^ (((pv >> 1) & 7) << 2);                           \
        const int rb  = pv * 4 * LROW + cc;                                    \
        _Pragma("unroll")                                                      \
        for (int r = 0; r < 4; ++r)                                            \
            *(unsigned int*)&y[rb + r * LROW] =                                \
                valid ? pk2(r0[i][r], r1[i][r]) : 0u;                          \
    }

    #define ZERO_ACC                                                           \
    {                                                                          \
        _Pragma("unroll")                                                      \
        for (int m = 0; m < 2; ++m)                                            \
            _Pragma("unroll")                                                  \
            for (int nn = 0; nn < 7; ++nn)                                     \
                acc[m][nn] = f32x4{0.f, 0.f, 0.f, 0.f};                        \
    }

    // swapped operands: D[p,o] = mfma(Y-frag as A, W-frag as B)
    #define COMPUTE(K0, K1)                                                    \
    {                                                                          \
        _Pragma("unroll")                                                      \
        for (int nn = 0; nn < 7; ++nn) {                                       \
            const int lp   = nn * 16 + ol;                                     \
            const int zz   = ((lp >> 3) & 7) << 2;                             \
            const int rowb = lp * LROW;                                        \
            _Pragma("unroll")                                                  \
            for (int kk = (K0); kk < (K1); ++kk) {                             \
                const int c  = kk * 32 + g * 8;                                \
                const int e0 = c ^ zz;                                         \
                const bf16x4 lo = *(const bf16x4*)&y[rowb + e0];               \
                const bf16x4 hi = *(const bf16x4*)&y[rowb + (e0 ^ 4)];         \
                const bf16x8 bf = __builtin_shufflevector(lo, hi,              \
                                                          0, 1, 2, 3, 4, 5, 6, 7); \
                _Pragma("unroll")                                              \
                for (int m = 0; m < 2; ++m)                                    \
                    acc[m][nn] = __builtin_amdgcn_mfma_f32_16x16x32_bf16(      \
                        bf, wf[kk][m], acc[m][nn], 0, 0, 0);                   \
            }                                                                  \
        }                                                                      \
    }

    // swapped C/D: col=lane&15 -> o sub-index; row=g*4+r -> pixel -> f32x4
    #define STORES(H)                                                          \
    {                                                                          \
        _Pragma("unroll")                                                      \
        for (int m = 0; m < 2; ++m) {                                          \
            const int o = (H) * 128 + wv * 32 + m * 16 + ol;                   \
            float* ob = out + (size_t)n * FRST + (size_t)o * HWPX + p0 + g * 4;\
            _Pragma("unroll")                                                  \
            for (int nn = 0; nn < 7; ++nn)                                     \
                *(f32x4*)(ob + nn * 16) = acc[m][nn];                          \
        }                                                                      \
    }

    // ---- prologue: h1(14), wfA(16), h2(14) --------------------------------
    #pragma unroll
    for (int i = 0; i < 7; ++i) ISSUE(i)
    WISSUE(0)
    #pragma unroll
    for (int i = 7; i < 14; ++i) ISSUE(i)

    asm volatile("s_waitcnt vmcnt(30)" ::: "memory");   // h1 ready
    __builtin_amdgcn_sched_barrier(0);
    #pragma unroll
    for (int i = 0; i < 7; ++i) WRITE_ITEM(i)
    __syncthreads();

    asm volatile("s_waitcnt vmcnt(14)" ::: "memory");   // wfA ready, h2 flying
    __builtin_amdgcn_sched_barrier(0);

    ZERO_ACC
    COMPUTE(0, 4)                                       // pass 1 (c < 128)

    asm volatile("s_waitcnt vmcnt(0)" ::: "memory");    // h2 ready
    __builtin_amdgcn_sched_barrier(0);
    #pragma unroll
    for (int i = 7; i < 14; ++i) WRITE_ITEM(i)
    __syncthreads();

    COMPUTE(4, 8)                                       // pass 2 (c >= 128)
    STORES(0)

    // ---- half 2: o >= 128. LDS is read-only now (no syncs needed) ---------
    WISSUE(1)
    asm volatile("s_waitcnt vmcnt(0)" ::: "memory");    // wfB (+stores) done
    __builtin_amdgcn_sched_barrier(0);

    ZERO_ACC
    COMPUTE(0, 8)
    STORES(1)

    #undef WISSUE
    #undef ISSUE
    #undef WRITE_ITEM
    #undef ZERO_ACC
    #undef COMPUTE
    #undef STORES
}

// ---- fallback (no workspace): R3 kernel, known-correct ---------------------
#define LDS_STRIDE 264
__global__ __launch_bounds__(512, 4)
void tsm_fallback(const float* __restrict__ x, const float* __restrict__ w,
                  float* __restrict__ out) {
    __shared__ __align__(16) unsigned short ylds[P_TILE * LDS_STRIDE];
    const int n = blockIdx.x, tile = blockIdx.y, p0 = tile * P_TILE;
    const int tid = threadIdx.x, tf = n & 7;
    f32x4 v0[7], v1[7]; int cps[7], pvs[7];
    #pragma unroll
    for (int i = 0; i < 7; ++i) {
        const int idx = tid + i * 512, cp = idx / 28, pv = idx - cp * 28;
        cps[i] = cp; pvs[i] = pv;
        const int c0 = cp * 2;
        int nsrc; bool valid;
        if (c0 < 32)      { nsrc = n - 1; valid = (tf > 0); }
        else if (c0 < 64) { nsrc = n + 1; valid = (tf < 7); }
        else              { nsrc = n;     valid = true; }
        const float* src = x + ((size_t)(valid ? nsrc : n) * CDIM + c0) * HWPX + p0 + pv * 4;
        f32x4 a = {0,0,0,0}, b = {0,0,0,0};
        if (valid) { a = *(const f32x4*)src; b = *(const f32x4*)(src + HWPX); }
        v0[i] = a; v1[i] = b;
    }
    #pragma unroll
    for (int i = 0; i < 7; ++i) {
        const int c0 = cps[i] * 2, pv = pvs[i];
        const int cc = c0 ^ ((pv & 7) << 3);
        const int rb = pv * 4 * LDS_STRIDE + cc;
        #pragma unroll
        for (int r = 0; r < 4; ++r)
            *(unsigned int*)&ylds[rb + r * LDS_STRIDE] = pk2(v0[i][r], v1[i][r]);
    }
    __syncthreads();
    const int lane = tid & 63, wv = tid >> 6, g = lane >> 4, ol = lane & 15;
    f32x4 acc[2][7];
    #pragma unroll
    for (int m = 0; m < 2; ++m)
        #pragma unroll
        for (int nn = 0; nn < 7; ++nn) acc[m][nn] = f32x4{0,0,0,0};
    #pragma unroll
    for (int kk = 0; kk < 8; ++kk) {
        const int c = kk * 32 + g * 8;
        bf16x8 af[2];
        #pragma unroll
        for (int m = 0; m < 2; ++m) {
            const float* wp = w + (size_t)(wv * 32 + m * 16 + ol) * CDIM + c;
            f32x4 w0 = *(const f32x4*)wp, w1 = *(const f32x4*)(wp + 4);
            union { bf16x8 v; unsigned int u4[4]; } cv;
            cv.u4[0] = pk2(w0[0], w0[1]); cv.u4[1] = pk2(w0[2], w0[3]);
            cv.u4[2] = pk2(w1[0], w1[1]); cv.u4[3] = pk2(w1[2], w1[3]);
            af[m] = cv.v;
        }
        #pragma unroll
        for (int nn = 0; nn < 7; ++nn) {
            const int p = nn * 16 + ol;
            const int cc = c ^ (((p >> 2) & 7) << 3);
            const bf16x8 bf = *(const bf16x8*)&ylds[p * LDS_STRIDE + cc];
            #pragma unroll
            for (int m = 0; m < 2; ++m)
                acc[m][nn] = __builtin_amdgcn_mfma_f32_16x16x32_bf16(af[m], bf, acc[m][nn], 0, 0, 0);
        }
    }
    const size_t outbase = (size_t)n * CDIM * HWPX + p0 + ol;
    #pragma unroll
    for (int m = 0; m < 2; ++m)
        #pragma unroll
        for (int r = 0; r < 4; ++r) {
            const int o = wv * 32 + m * 16 + g * 4 + r;
            float* orow = out + outbase + (size_t)o * HWPX;
            #pragma unroll
            for (int nn = 0; nn < 7; ++nn) orow[nn * 16] = acc[m][nn][r];
        }
}

extern "C" void kernel_launch(void* const* d_in, const int* in_sizes, int n_in,
                              void* d_out, int out_size, void* d_ws, size_t ws_size,
                              hipStream_t stream) {
    const float* x = (const float*)d_in[0];
    const float* w = (const float*)d_in[1];
    float* out     = (float*)d_out;
    const size_t wb_bytes = (size_t)CDIM * CDIM * sizeof(unsigned short); // 128KB
    if (ws_size >= wb_bytes) {
        unsigned short* wbuf = (unsigned short*)d_ws;
        wconv<<<64, 256, 0, stream>>>(w, wbuf);
        tsm_dedup<<<NWG, 256, 0, stream>>>(x, wbuf, out);
    } else {
        tsm_fallback<<<dim3(128, 7, 1), dim3(512, 1, 1), 0, stream>>>(x, w, out);
    }
}

// Round 14
// 56.211 us; speedup vs baseline: 1.8295x; 1.0310x over previous
//
#include <hip/hip_runtime.h>
#include <hip/hip_bf16.h>

// TSM temporal shift + 1x1 conv (256->256) fused as bf16 MFMA GEMM.
// x: [128, 256, 28, 28] f32, w: [256, 256] f32, out: [128, 256, 28, 28] f32.
// out[n,o,p] = sum_c W[o,c] * Y_n[c,p],
//   Y_n[c,p] = x[n-1,c,p] (c<32, t>0), x[n+1,c,p] (32<=c<64, t<7), x[n,c,p] else.
//
// R14 = R13 with a non-draining tail (the R13 regression mechanism).
//  R13's tail "STORES(0) -> WISSUE(1) -> vmcnt(0)" drained the 14 in-flight
//  output stores before half-2 compute -> ~half of each block ran with an
//  empty memory pipe (3.5 TB/s vs R10's saturated 6.3). Fix (ordering only):
//    pass2 -> WISSUE(1)[16 loads] -> STORES(0)[14 stores] -> vmcnt(14)
//  In-order vmcnt retirement (m135) => drains exactly wfB, leaves all 14
//  stores flying; half-2 compute overlaps the store stream.
//  Everything else identical to R13 (passed, absmax 0.03125): single x read
//  per tile (203MB CU-side, floor ~33us), 28-deep asm staging, counted
//  vmcnt(30)/(14)/(0) prologue, 4-bf16 swizzle pair, swapped-operand MFMA
//  (D[p,o]) giving 14 dwordx4 stores per half.

#define CDIM 256
#define HWPX 784
#define FRST (CDIM * HWPX)        // 200704 floats per frame
#define P_TILE 112
#define NPT  7                    // 112-px tiles per frame
#define NWG  (128 * NPT)          // 896 blocks, % 8 == 0
#define LROW 264                  // bf16 per LDS pixel row (528 B)

using bf16x8 = __attribute__((ext_vector_type(8))) short;
using bf16x4 = __attribute__((ext_vector_type(4))) short;
using f32x4  = __attribute__((ext_vector_type(4))) float;

static __device__ __forceinline__ unsigned int pk2(float lo, float hi) {
    union { __hip_bfloat162 h; unsigned int u; } cv;
    cv.h = __float22bfloat162_rn(make_float2(lo, hi));
    return cv.u;
}

// ---- W f32 -> bf16 row-major (one-shot) ------------------------------------
__global__ void wconv(const float* __restrict__ w, unsigned short* __restrict__ wb) {
    const int i = (blockIdx.x * 256 + threadIdx.x) * 4;
    f32x4 v = *(const f32x4*)(w + i);
    *(uint2*)(wb + i) = make_uint2(pk2(v[0], v[1]), pk2(v[2], v[3]));
}

__global__ __launch_bounds__(256, 2)   // 256-reg budget, 2 blocks/CU (LDS-capped)
void tsm_dedup2(const float* __restrict__ x,
                const unsigned short* __restrict__ wb,
                float* __restrict__ out) {
    __shared__ __align__(16) unsigned short y[P_TILE * LROW];   // 59136 B

    const int bid = blockIdx.x;
    const int wg  = (bid & 7) * (NWG / 8) + (bid >> 3);   // XCD-bijective
    const int n   = wg / NPT;             // frame
    const int pt  = wg - n * NPT;
    const int p0  = pt * P_TILE;
    const int tid = threadIdx.x;
    const int tf  = n & 7;

    const int lane = tid & 63;
    const int wv   = tid >> 6;            // wave -> 32 out-ch per half
    const int g    = lane >> 4;
    const int ol   = lane & 15;

    bf16x8 wf[8][2];                      // W frags for current half
    f32x4  r0[14], r1[14];
    f32x4  acc[2][7];

    #define WISSUE(H)                                                          \
    {                                                                          \
        _Pragma("unroll")                                                      \
        for (int kk = 0; kk < 8; ++kk)                                         \
            _Pragma("unroll")                                                  \
            for (int m = 0; m < 2; ++m) {                                      \
                const unsigned short* wp_ =                                    \
                    &wb[(size_t)((H) * 128 + wv * 32 + m * 16 + ol) * CDIM     \
                        + kk * 32 + g * 8];                                    \
                asm volatile("global_load_dwordx4 %0, %1, off"                 \
                             : "=v"(wf[kk][m]) : "v"(wp_));                    \
            }                                                                  \
    }

    #define ISSUE(i)                                                           \
    {                                                                          \
        const int idx = tid + (i) * 256;                                       \
        const int cp  = idx / 28;                                              \
        const int pv  = idx - cp * 28;                                         \
        const int c0  = cp * 2;                                                \
        const int d   = (cp < 16) ? -1 : (cp < 32 ? 1 : 0);                    \
        const bool valid = !((d == -1 && tf == 0) || (d == 1 && tf == 7));     \
        const float* s = x + ((size_t)(n + (valid ? d : 0)) * CDIM + c0) * HWPX\
                           + p0 + pv * 4;                                      \
        asm volatile("global_load_dwordx4 %0, %1, off" : "=v"(r0[i]) : "v"(s));\
        const float* s1 = s + HWPX;                                            \
        asm volatile("global_load_dwordx4 %0, %1, off" : "=v"(r1[i]) : "v"(s1));\
    }

    #define WRITE_ITEM(i)                                                      \
    {                                                                          \
        const int idx = tid + (i) * 256;                                       \
        const int cp  = idx / 28;                                              \
        const int pv  = idx - cp * 28;                                         \
        const int c0  = cp * 2;                                                \
        const int d   = (cp < 16) ? -1 : (cp < 32 ? 1 : 0);                    \
        const bool valid = !((d == -1 && tf == 0) || (d == 1 && tf == 7));     \
        const int cc  = c0 ^ (((pv >> 1) & 7) << 2);                           \
        const int rb  = pv * 4 * LROW + cc;                                    \
        _Pragma("unroll")                                                      \
        for (int r = 0; r < 4; ++r)                                            \
            *(unsigned int*)&y[rb + r * LROW] =                                \
                valid ? pk2(r0[i][r], r1[i][r]) : 0u;                          \
    }

    #define ZERO_ACC                                                           \
    {                                                                          \
        _Pragma("unroll")                                                      \
        for (int m = 0; m < 2; ++m)                                            \
            _Pragma("unroll")                                                  \
            for (int nn = 0; nn < 7; ++nn)                                     \
                acc[m][nn] = f32x4{0.f, 0.f, 0.f, 0.f};                        \
    }

    // swapped operands: D[p,o] = mfma(Y-frag as A, W-frag as B)
    #define COMPUTE(K0, K1)                                                    \
    {                                                                          \
        _Pragma("unroll")                                                      \
        for (int nn = 0; nn < 7; ++nn) {                                       \
            const int lp   = nn * 16 + ol;                                     \
            const int zz   = ((lp >> 3) & 7) << 2;                             \
            const int rowb = lp * LROW;                                        \
            _Pragma("unroll")                                                  \
            for (int kk = (K0); kk < (K1); ++kk) {                             \
                const int c  = kk * 32 + g * 8;                                \
                const int e0 = c ^ zz;                                         \
                const bf16x4 lo = *(const bf16x4*)&y[rowb + e0];               \
                const bf16x4 hi = *(const bf16x4*)&y[rowb + (e0 ^ 4)];         \
                const bf16x8 bf = __builtin_shufflevector(lo, hi,              \
                                                          0, 1, 2, 3, 4, 5, 6, 7); \
                _Pragma("unroll")                                              \
                for (int m = 0; m < 2; ++m)                                    \
                    acc[m][nn] = __builtin_amdgcn_mfma_f32_16x16x32_bf16(      \
                        bf, wf[kk][m], acc[m][nn], 0, 0, 0);                   \
            }                                                                  \
        }                                                                      \
    }

    // swapped C/D: col=lane&15 -> o sub-index; row=g*4+r -> pixel -> f32x4
    #define STORES(H)                                                          \
    {                                                                          \
        _Pragma("unroll")                                                      \
        for (int m = 0; m < 2; ++m) {                                          \
            const int o = (H) * 128 + wv * 32 + m * 16 + ol;                   \
            float* ob = out + (size_t)n * FRST + (size_t)o * HWPX + p0 + g * 4;\
            _Pragma("unroll")                                                  \
            for (int nn = 0; nn < 7; ++nn)                                     \
                *(f32x4*)(ob + nn * 16) = acc[m][nn];                          \
        }                                                                      \
    }

    // ---- prologue: h1(14), wfA(16), h2(14) --------------------------------
    #pragma unroll
    for (int i = 0; i < 7; ++i) ISSUE(i)
    WISSUE(0)
    #pragma unroll
    for (int i = 7; i < 14; ++i) ISSUE(i)

    asm volatile("s_waitcnt vmcnt(30)" ::: "memory");   // h1 ready
    __builtin_amdgcn_sched_barrier(0);
    #pragma unroll
    for (int i = 0; i < 7; ++i) WRITE_ITEM(i)
    __syncthreads();

    asm volatile("s_waitcnt vmcnt(14)" ::: "memory");   // wfA ready, h2 flying
    __builtin_amdgcn_sched_barrier(0);

    ZERO_ACC
    COMPUTE(0, 4)                                       // pass 1 (c < 128)

    asm volatile("s_waitcnt vmcnt(0)" ::: "memory");    // h2 ready
    __builtin_amdgcn_sched_barrier(0);
    #pragma unroll
    for (int i = 7; i < 14; ++i) WRITE_ITEM(i)
    __syncthreads();

    COMPUTE(4, 8)                                       // pass 2 (c >= 128)

    // ---- non-draining tail: wfB first, then stores, counted wait ----------
    WISSUE(1)                                           // 16 loads (oldest)
    STORES(0)                                           // 14 stores (newest)
    asm volatile("s_waitcnt vmcnt(14)" ::: "memory");   // drain wfB only
    __builtin_amdgcn_sched_barrier(0);

    ZERO_ACC
    COMPUTE(0, 8)                                       // half 2, LDS read-only
    STORES(1)

    #undef WISSUE
    #undef ISSUE
    #undef WRITE_ITEM
    #undef ZERO_ACC
    #undef COMPUTE
    #undef STORES
}

// ---- fallback (no workspace): R3 kernel, known-correct ---------------------
#define LDS_STRIDE 264
__global__ __launch_bounds__(512, 4)
void tsm_fallback(const float* __restrict__ x, const float* __restrict__ w,
                  float* __restrict__ out) {
    __shared__ __align__(16) unsigned short ylds[P_TILE * LDS_STRIDE];
    const int n = blockIdx.x, tile = blockIdx.y, p0 = tile * P_TILE;
    const int tid = threadIdx.x, tf = n & 7;
    f32x4 v0[7], v1[7]; int cps[7], pvs[7];
    #pragma unroll
    for (int i = 0; i < 7; ++i) {
        const int idx = tid + i * 512, cp = idx / 28, pv = idx - cp * 28;
        cps[i] = cp; pvs[i] = pv;
        const int c0 = cp * 2;
        int nsrc; bool valid;
        if (c0 < 32)      { nsrc = n - 1; valid = (tf > 0); }
        else if (c0 < 64) { nsrc = n + 1; valid = (tf < 7); }
        else              { nsrc = n;     valid = true; }
        const float* src = x + ((size_t)(valid ? nsrc : n) * CDIM + c0) * HWPX + p0 + pv * 4;
        f32x4 a = {0,0,0,0}, b = {0,0,0,0};
        if (valid) { a = *(const f32x4*)src; b = *(const f32x4*)(src + HWPX); }
        v0[i] = a; v1[i] = b;
    }
    #pragma unroll
    for (int i = 0; i < 7; ++i) {
        const int c0 = cps[i] * 2, pv = pvs[i];
        const int cc = c0 ^ ((pv & 7) << 3);
        const int rb = pv * 4 * LDS_STRIDE + cc;
        #pragma unroll
        for (int r = 0; r < 4; ++r)
            *(unsigned int*)&ylds[rb + r * LDS_STRIDE] = pk2(v0[i][r], v1[i][r]);
    }
    __syncthreads();
    const int lane = tid & 63, wv = tid >> 6, g = lane >> 4, ol = lane & 15;
    f32x4 acc[2][7];
    #pragma unroll
    for (int m = 0; m < 2; ++m)
        #pragma unroll
        for (int nn = 0; nn < 7; ++nn) acc[m][nn] = f32x4{0,0,0,0};
    #pragma unroll
    for (int kk = 0; kk < 8; ++kk) {
        const int c = kk * 32 + g * 8;
        bf16x8 af[2];
        #pragma unroll
        for (int m = 0; m < 2; ++m) {
            const float* wp = w + (size_t)(wv * 32 + m * 16 + ol) * CDIM + c;
            f32x4 w0 = *(const f32x4*)wp, w1 = *(const f32x4*)(wp + 4);
            union { bf16x8 v; unsigned int u4[4]; } cv;
            cv.u4[0] = pk2(w0[0], w0[1]); cv.u4[1] = pk2(w0[2], w0[3]);
            cv.u4[2] = pk2(w1[0], w1[1]); cv.u4[3] = pk2(w1[2], w1[3]);
            af[m] = cv.v;
        }
        #pragma unroll
        for (int nn = 0; nn < 7; ++nn) {
            const int p = nn * 16 + ol;
            const int cc = c ^ (((p >> 2) & 7) << 3);
            const bf16x8 bf = *(const bf16x8*)&ylds[p * LDS_STRIDE + cc];
            #pragma unroll
            for (int m = 0; m < 2; ++m)
                acc[m][nn] = __builtin_amdgcn_mfma_f32_16x16x32_bf16(af[m], bf, acc[m][nn], 0, 0, 0);
        }
    }
    const size_t outbase = (size_t)n * CDIM * HWPX + p0 + ol;
    #pragma unroll
    for (int m = 0; m < 2; ++m)
        #pragma unroll
        for (int r = 0; r < 4; ++r) {
            const int o = wv * 32 + m * 16 + g * 4 + r;
            float* orow = out + outbase + (size_t)o * HWPX;
            #pragma unroll
            for (int nn = 0; nn < 7; ++nn) orow[nn * 16] = acc[m][nn][r];
        }
}

extern "C" void kernel_launch(void* const* d_in, const int* in_sizes, int n_in,
                              void* d_out, int out_size, void* d_ws, size_t ws_size,
                              hipStream_t stream) {
    const float* x = (const float*)d_in[0];
    const float* w = (const float*)d_in[1];
    float* out     = (float*)d_out;
    const size_t wb_bytes = (size_t)CDIM * CDIM * sizeof(unsigned short); // 128KB
    if (ws_size >= wb_bytes) {
        unsigned short* wbuf = (unsigned short*)d_ws;
        wconv<<<64, 256, 0, stream>>>(w, wbuf);
        tsm_dedup2<<<NWG, 256, 0, stream>>>(x, wbuf, out);
    } else {
        tsm_fallback<<<dim3(128, 7, 1), dim3(512, 1, 1), 0, stream>>>(x, w, out);
    }
}